// Round 9
// baseline (142.406 us; speedup 1.0000x reference)
//
#include <hip/hip_runtime.h>
#include <math.h>

// Problem dims
#define S_   8
#define B_   16
#define D_   10
#define N_   32
#define E_   300
#define H_   128
#define G4_  512
#define SDIM_ 96
#define MID_ 256
#define TOT_ 528

#define NWPACK 3850240   // 8*47*320*32  (wpack2)
#define NWPRE  1310720   // 8*10*512*32  (wpre2)

// prep grid-stride unit ranges
#define U_WPACK  481280          // NWPACK/8
#define U_WPRE   645120          // +163840
#define U_LXWT   907264          // +262144
#define U_LYWT   972800          // +65536
#define U_AW1T   1107968         // +135168
#define U_BCOMB  1110528         // +2560

typedef unsigned short u16;
typedef __attribute__((ext_vector_type(8))) short short8;
typedef __attribute__((ext_vector_type(4))) short short4v;
typedef __attribute__((ext_vector_type(4))) float f32x4;

// round-to-nearest-even f32 -> bf16
static __device__ __forceinline__ u16 f2bf(float f) {
    unsigned u = __builtin_bit_cast(unsigned, f);
    return (u16)((u + 0x7FFFu + ((u >> 16) & 1u)) >> 16);
}

// ---------------------------------------------------------------------------
// prep (grid-stride, octet-vectorized): wpack2[s][ks][c][q][8] bf16,
// wpre2[s][ks][g][q][8] bf16, bcomb, lxwT, lywT, aw1T.
// ---------------------------------------------------------------------------
__global__ void prep(const float* __restrict__ w3, const float* __restrict__ b3,
                     const float* __restrict__ w4, const float* __restrict__ b4,
                     const float* __restrict__ w5, const float* __restrict__ b5,
                     const float* __restrict__ w_ih,
                     const float* __restrict__ lxw, const float* __restrict__ lyw,
                     const float* __restrict__ aw1,
                     u16* __restrict__ wpack2, u16* __restrict__ wpre2,
                     float* __restrict__ bcomb,
                     float* __restrict__ lxwT, float* __restrict__ lywT,
                     float* __restrict__ aw1T) {
    const int stride = gridDim.x * blockDim.x;
    for (int u = blockIdx.x * blockDim.x + threadIdx.x; u < U_BCOMB; u += stride) {
        if (u < U_WPACK) {
            // unit -> (s,ks,c,q), writes 8 u16 at u*8
            int q = u & 3, t = u >> 2;
            int c = t % 320, t2 = t / 320;
            int ks = t2 % 47, s = t2 / 47;
            u16 o[8];
#pragma unroll
            for (int j = 0; j < 8; ++j) {
                int kk = ks * 32 + q * 8 + j;
                int tap = kk / 300, e = kk - tap * 300;
                float v = 0.f;
                if (tap < 5) {
                    if (c < 100)      { if (tap < 3) v = w3[((s*100 + c      )*300 + e)*3 + tap]; }
                    else if (c < 200) { if (tap < 4) v = w4[((s*100 + c - 100)*300 + e)*4 + tap]; }
                    else if (c < 300) {              v = w5[((s*100 + c - 200)*300 + e)*5 + tap]; }
                }
                o[j] = f2bf(v);
            }
            *reinterpret_cast<ushort4*>(&wpack2[u * 8])     = make_ushort4(o[0], o[1], o[2], o[3]);
            *reinterpret_cast<ushort4*>(&wpack2[u * 8 + 4]) = make_ushort4(o[4], o[5], o[6], o[7]);
        } else if (u < U_WPRE) {
            int u2 = u - U_WPACK;
            int q = u2 & 3, t = u2 >> 2;
            int g = t & 511, t2 = t >> 9;
            int ks = t2 % 10, s = t2 / 10;
            u16 o[8];
#pragma unroll
            for (int j = 0; j < 8; ++j) {
                int kk = ks * 32 + q * 8 + j;
                float v = (kk < 300) ? w_ih[((size_t)s * 512 + g) * 300 + kk] : 0.f;
                o[j] = f2bf(v);
            }
            *reinterpret_cast<ushort4*>(&wpre2[u2 * 8])     = make_ushort4(o[0], o[1], o[2], o[3]);
            *reinterpret_cast<ushort4*>(&wpre2[u2 * 8 + 4]) = make_ushort4(o[4], o[5], o[6], o[7]);
        } else if (u < U_LXWT) {
            int i = u - U_WPRE;          // lxwT[s][i256][t128]
            int t = i & 127, ii = (i >> 7) & 255, s = i >> 15;
            lxwT[i] = lxw[((size_t)(s * 128 + t)) * 256 + ii];
        } else if (u < U_LYWT) {
            int i = u - U_LXWT;          // lywT[s][i128][t64]
            int t = i & 63, ii = (i >> 6) & 127, s = i >> 13;
            lywT[i] = lyw[((size_t)(s * 64 + t)) * 128 + ii];
        } else if (u < U_AW1T) {
            int i = u - U_LYWT;          // aw1T[i528][j256]
            int j = i & 255, ii = i >> 8;
            aw1T[i] = aw1[(size_t)j * TOT_ + ii];
        } else {
            int i = u - U_AW1T;          // bcomb[s][320]
            int c = i % 320, s = i / 320;
            float bv = 0.f;
            if (c < 100)      bv = b3[s*100 + c];
            else if (c < 200) bv = b4[s*100 + c - 100];
            else if (c < 300) bv = b5[s*100 + c - 200];
            bcomb[i] = bv;
        }
    }
}

// ---------------------------------------------------------------------------
// conv via MFMA: block per (s,b,half) = 5 days, 512 thr = 8 waves (2m x 4n),
// wave C[80][80] = 5x5 16x16 tiles. A from xs LDS (window trick). B direct
// global->VGPR coalesced (wpack2) with 2-deep register prefetch. No K-loop
// barriers, no setprio. x staging batched 8-deep for MLP.
// ---------------------------------------------------------------------------
__global__ __launch_bounds__(512, 1) void conv_mfma(const float* __restrict__ news,
                                                    const u16* __restrict__ wpack2,
                                                    const float* __restrict__ bcomb,
                                                    u16* __restrict__ text_bf) {
    __shared__ u16 xs[5 * 10816];
    __shared__ float part[10][320];
    const int tid = threadIdx.x, bid = blockIdx.x;
    const int s = bid & 7, rr_ = bid >> 3, b = rr_ >> 1, half = rr_ & 1;
    const int l = tid & 63, wvi = tid >> 6;
    const int wm = wvi >> 2, wn = wvi & 3;
    const int q = l >> 4, r16 = l & 15;

    // B-frag pointers: u16 idx = s*481280 + ks*10240 + c*32 + q*8
    const u16* gp[5];
#pragma unroll
    for (int nt = 0; nt < 5; ++nt) {
        int c = wn * 80 + nt * 16 + r16;
        gp[nt] = wpack2 + (size_t)s * 481280 + c * 32 + q * 8;
    }

    // prologue B prefetch (ks=0,1) issued BEFORE the staging barrier
    short8 bf0[5], bf1[5];
#pragma unroll
    for (int nt = 0; nt < 5; ++nt) bf0[nt] = *reinterpret_cast<const short8*>(gp[nt]);
#pragma unroll
    for (int nt = 0; nt < 5; ++nt) bf1[nt] = *reinterpret_cast<const short8*>(gp[nt] + 10240);

    // stage 5 days f32->bf16 with 8-deep load batches (MLP)
    {
        const float4* xg = reinterpret_cast<const float4*>(
            news + (size_t)((b * 8 + s) * 10 + half * 5) * 9600);   // 5 contiguous days
        for (int base = 0; base < 12000; base += 4096) {            // 3 batches of 8x512
            float4 v[8];
#pragma unroll
            for (int j = 0; j < 8; ++j) {
                int idx = base + j * 512 + tid;
                if (idx < 12000) v[j] = xg[idx];
            }
#pragma unroll
            for (int j = 0; j < 8; ++j) {
                int idx = base + j * 512 + tid;
                if (idx < 12000) {
                    int day = idx / 2400, rem = idx - day * 2400;
                    ushort4 o;
                    o.x = f2bf(v[j].x); o.y = f2bf(v[j].y);
                    o.z = f2bf(v[j].z); o.w = f2bf(v[j].w);
                    *reinterpret_cast<ushort4*>(&xs[day * 10816 + rem * 4]) = o;
                }
            }
        }
        // zero pads: per day elements [9600, 10816) = 1216 u16 = 304 u32
        for (int i = tid; i < 1520; i += 512) {
            int day = i / 304, p = i - day * 304;
            *reinterpret_cast<unsigned*>(&xs[day * 10816 + 9600 + p * 2]) = 0u;
        }
    }
    __syncthreads();

    f32x4 acc[5][5];   // [m-tile][n-tile]
#pragma unroll
    for (int mt = 0; mt < 5; ++mt)
#pragma unroll
        for (int nt = 0; nt < 5; ++nt) acc[mt][nt] = (f32x4)(0.f);

#define LOADA(dst, ks) do {                                                       \
    _Pragma("unroll")                                                             \
    for (int mt_ = 0; mt_ < 5; ++mt_) {                                           \
        int di_ = wm * 5 + mt_;                                                   \
        int off_ = (di_ >> 1) * 10816 + (((di_ & 1) << 4) + r16) * 300            \
                   + (ks) * 32 + q * 8;                                           \
        short4v lo_ = *reinterpret_cast<const short4v*>(&xs[off_]);               \
        short4v hi_ = *reinterpret_cast<const short4v*>(&xs[off_ + 4]);           \
        dst[mt_] = __builtin_shufflevector(lo_, hi_, 0, 1, 2, 3, 4, 5, 6, 7);     \
    } } while (0)

#define MFMAS(bfv, av) do {                                                       \
    _Pragma("unroll")                                                             \
    for (int nt_ = 0; nt_ < 5; ++nt_)                                             \
        _Pragma("unroll")                                                         \
        for (int mt_ = 0; mt_ < 5; ++mt_)                                         \
            acc[mt_][nt_] = __builtin_amdgcn_mfma_f32_16x16x32_bf16(av[mt_], bfv[nt_], acc[mt_][nt_], 0, 0, 0); \
    } while (0)

    for (int ks = 0; ks < 46; ks += 2) {
        short8 a0[5], a1[5];
        LOADA(a0, ks);
        MFMAS(bf0, a0);
#pragma unroll
        for (int nt = 0; nt < 5; ++nt)
            bf0[nt] = *reinterpret_cast<const short8*>(gp[nt] + (ks + 2) * 10240);

        LOADA(a1, ks + 1);
        MFMAS(bf1, a1);
        if (ks + 3 < 47) {
#pragma unroll
            for (int nt = 0; nt < 5; ++nt)
                bf1[nt] = *reinterpret_cast<const short8*>(gp[nt] + (ks + 3) * 10240);
        }
    }
    {   // ks = 46 tail
        short8 a0[5];
        LOADA(a0, 46);
        MFMAS(bf0, a0);
    }
#undef LOADA
#undef MFMAS

    // epilogue: per-wave masked max -> LDS partials, then combine day-halves
#pragma unroll
    for (int mt = 0; mt < 5; ++mt) {
        const int di = wm * 5 + mt;
        const int nwb = (di & 1) << 4;
#pragma unroll
        for (int nt = 0; nt < 5; ++nt) {
            int oc = wn * 80 + nt * 16 + r16;
            int L = (oc < 100) ? 30 : (oc < 200) ? 29 : 28;
            float mx = -3e38f;
#pragma unroll
            for (int rr = 0; rr < 4; ++rr) {
                int nw = nwb + q * 4 + rr;
                if (nw < L) mx = fmaxf(mx, acc[mt][nt][rr]);
            }
            mx = fmaxf(mx, __shfl_xor(mx, 16));
            mx = fmaxf(mx, __shfl_xor(mx, 32));
            if (l < 16) part[di][wn * 80 + nt * 16 + l] = mx;
        }
    }
    __syncthreads();
    for (int i = tid; i < 1600; i += 512) {
        int day = i / 320, oc = i - day * 320;
        float mx = fmaxf(part[2 * day][oc], part[2 * day + 1][oc]);
        text_bf[((size_t)(s * 16 + b) * 10 + half * 5 + day) * 320 + oc] =
            f2bf(mx + bcomb[s * 320 + oc]);
    }
}

// ---------------------------------------------------------------------------
// lstm_pre via MFMA: per (s,d): pre[16b][512g] = text[16][320] x wpre[320][512]
// A in XOR-swizzled LDS; B direct global->VGPR, coalesced via wpre2 layout.
// ---------------------------------------------------------------------------
__global__ __launch_bounds__(256) void lstm_pre_mfma(const u16* __restrict__ text_bf,
                                                     const u16* __restrict__ wpre2,
                                                     const float* __restrict__ b_ih,
                                                     const float* __restrict__ b_hh,
                                                     float* __restrict__ pre) {
    __shared__ u16 as16[16 * 320];
    const int sd = blockIdx.x, s = sd / 10, d = sd % 10;
    const int tid = threadIdx.x, l = tid & 63, w = tid >> 6, q = l >> 4, r16 = l & 15;

    // stage A (16 rows x 640B), XOR-swizzle 16B chunks: chunk' = chunk ^ (row&7)
    for (int i = tid; i < 640; i += 256) {
        int r = i / 40, c = i % 40;
        *reinterpret_cast<float4*>(as16 + r * 320 + ((c ^ (r & 7)) << 3)) =
            *reinterpret_cast<const float4*>(text_bf + ((size_t)(s * 16 + r) * 10 + d) * 320 + c * 8);
    }
    __syncthreads();

    // u16 idx = s*163840 + ks*16384 + g*32 + q*8
    const u16* gpb[8];
#pragma unroll
    for (int nt = 0; nt < 8; ++nt) {
        int g = w * 128 + nt * 16 + r16;
        gpb[nt] = wpre2 + (size_t)s * 163840 + g * 32 + q * 8;
    }

    f32x4 acc[8];
#pragma unroll
    for (int nt = 0; nt < 8; ++nt) acc[nt] = (f32x4)(0.f);

    for (int ks = 0; ks < 10; ++ks) {
        short8 a = *reinterpret_cast<const short8*>(
            as16 + r16 * 320 + (((ks * 4 + q) ^ (r16 & 7)) << 3));
#pragma unroll
        for (int nt = 0; nt < 8; ++nt) {
            short8 bf = *reinterpret_cast<const short8*>(gpb[nt] + ks * 16384);
            acc[nt] = __builtin_amdgcn_mfma_f32_16x16x32_bf16(a, bf, acc[nt], 0, 0, 0);
        }
    }

#pragma unroll
    for (int nt = 0; nt < 8; ++nt) {
        int g = w * 128 + nt * 16 + r16;
        float bias = b_ih[s * 512 + g] + b_hh[s * 512 + g];
#pragma unroll
        for (int r = 0; r < 4; ++r) {
            int brow = q * 4 + r;
            pre[((size_t)sd * 16 + brow) * 512 + g] = acc[nt][r] + bias;
        }
    }
}

// ---------------------------------------------------------------------------
// lstm_tail: sequential LSTM + degenerate attention + linX + linY (fused).
// ---------------------------------------------------------------------------
__global__ __launch_bounds__(512) void lstm_tail(const float* __restrict__ pre,
                                                 const float* __restrict__ w_hh,
                                                 const float* __restrict__ lxwT, const float* __restrict__ lxb,
                                                 const float* __restrict__ lywT, const float* __restrict__ lyb,
                                                 float* __restrict__ total) {
    __shared__ float wchunk[128][129];
    __shared__ float h_lds[H_];
    __shared__ float gates[G4_];
    __shared__ float comb_l[256];
    __shared__ __align__(16) float hx[H_];
    const int sb = blockIdx.x;
    const int s = sb / B_, b = sb % B_;
    const int t = threadIdx.x;

    // stage w_hh[s] rows into per-thread regs, coalesced via LDS
    float wrs[128];
    for (int c = 0; c < 4; ++c) {
        for (int i2 = t; i2 < 128 * 32; i2 += 512) {
            int row = i2 >> 5, fq = i2 & 31;
            float4 v = *reinterpret_cast<const float4*>(
                w_hh + ((size_t)(s * G4_ + c * 128 + row)) * H_ + fq * 4);
            wchunk[row][fq * 4 + 0] = v.x; wchunk[row][fq * 4 + 1] = v.y;
            wchunk[row][fq * 4 + 2] = v.z; wchunk[row][fq * 4 + 3] = v.w;
        }
        __syncthreads();
        if ((t >> 7) == c) {
            int r = t & 127;
#pragma unroll
            for (int i = 0; i < 128; ++i) wrs[i] = wchunk[r][i];
        }
        __syncthreads();
    }

    float cc = 0.f, hsum = 0.f, hval = 0.f;
    if (t < H_) h_lds[t] = 0.f;
    __syncthreads();

    for (int d = 0; d < D_; ++d) {
        float a0 = pre[(((size_t)(s * D_ + d) * B_ + b)) * G4_ + t];
        float a1 = 0.f, a2 = 0.f, a3 = 0.f;
#pragma unroll
        for (int i = 0; i < 128; i += 4) {
            float4 h4 = *reinterpret_cast<const float4*>(&h_lds[i]);
            a0 = fmaf(wrs[i + 0], h4.x, a0);
            a1 = fmaf(wrs[i + 1], h4.y, a1);
            a2 = fmaf(wrs[i + 2], h4.z, a2);
            a3 = fmaf(wrs[i + 3], h4.w, a3);
        }
        gates[t] = (a0 + a1) + (a2 + a3);
        __syncthreads();
        if (t < H_) {
            float ig = 1.f / (1.f + expf(-gates[t]));
            float fg = 1.f / (1.f + expf(-gates[H_ + t]));
            float gg = tanhf(gates[2 * H_ + t]);
            float og = 1.f / (1.f + expf(-gates[3 * H_ + t]));
            cc = fg * cc + ig * gg;
            hval = og * tanhf(cc);
            hsum += hval;
            h_lds[t] = hval;
        }
        __syncthreads();
    }
    if (t < H_) { comb_l[t] = hval; comb_l[H_ + t] = hsum; }
    __syncthreads();
    if (t < H_) {                       // linX: coalesced lxwT[s][i][t]
        const float* wv = lxwT + (size_t)s * 256 * 128 + t;
        float a0 = lxb[s * H_ + t], a1 = 0.f;
        for (int i = 0; i < 256; i += 2) {
            a0 = fmaf(comb_l[i], wv[(size_t)i * 128], a0);
            a1 = fmaf(comb_l[i + 1], wv[(size_t)(i + 1) * 128], a1);
        }
        hx[t] = fmaxf(a0 + a1, 0.f);
    }
    __syncthreads();
    if (t < 64) {                       // linY: coalesced lywT[s][i][t]
        const float* wv = lywT + (size_t)s * 128 * 64 + t;
        float a0 = lyb[s * 64 + t], a1 = 0.f;
        for (int i = 0; i < 128; i += 2) {
            a0 = fmaf(hx[i], wv[(size_t)i * 64], a0);
            a1 = fmaf(hx[i + 1], wv[(size_t)(i + 1) * 64], a1);
        }
        total[(size_t)b * 512 + s * 64 + t] = fmaxf(a0 + a1, 0.f);
    }
}

// ---------------------------------------------------------------------------
// head_feats: feats MLP + arch head fused; aw1T coalesced; split-K partials.
// ---------------------------------------------------------------------------
__global__ __launch_bounds__(512) void head_feats(const float* __restrict__ total,
                                                  const float* __restrict__ sf,
                                                  const float* __restrict__ w1, const float* __restrict__ b1,
                                                  const float* __restrict__ w2, const float* __restrict__ b2,
                                                  const float* __restrict__ aw1T, const float* __restrict__ ab1,
                                                  const float* __restrict__ aw2, const float* __restrict__ ab2,
                                                  const float* __restrict__ avar,
                                                  float* __restrict__ out) {
    __shared__ __align__(16) float tr[TOT_];
    __shared__ float hid[MID_];
    __shared__ float h1f[24];
    __shared__ float pA[MID_], pB[MID_];
    const int bb = blockIdx.x, t = threadIdx.x;
    if (t < 128)
        reinterpret_cast<float4*>(tr)[t] = reinterpret_cast<const float4*>(total + (size_t)bb * 512)[t];
    if (t < 24) {
        float acc = b1[t];
        for (int i = 0; i < SDIM_; ++i) acc = fmaf(sf[bb * SDIM_ + i], w1[t * SDIM_ + i], acc);
        h1f[t] = fmaxf(acc, 0.f);
    }
    __syncthreads();
    if (t < 16) {
        float acc = b2[t];
        for (int i = 0; i < 24; ++i) acc = fmaf(h1f[i], w2[t * 24 + i], acc);
        tr[512 + t] = acc;
    }
    __syncthreads();
    {   // layer1 split-K: threads [0,256) do i in [0,264); [256,512) do [264,528)
        const int j = t & 255, hf = t >> 8;
        const int ilo = hf ? 264 : 0, ihi = hf ? 528 : 264;
        const float* wv = aw1T + j;
        float a0 = 0.f, a1 = 0.f, a2 = 0.f, a3 = 0.f;
        for (int i = ilo; i < ihi; i += 4) {
            a0 = fmaf(tr[i + 0], wv[(size_t)(i + 0) * 256], a0);
            a1 = fmaf(tr[i + 1], wv[(size_t)(i + 1) * 256], a1);
            a2 = fmaf(tr[i + 2], wv[(size_t)(i + 2) * 256], a2);
            a3 = fmaf(tr[i + 3], wv[(size_t)(i + 3) * 256], a3);
        }
        float p = (a0 + a1) + (a2 + a3);
        if (hf) pB[j] = p; else pA[j] = p;
    }
    __syncthreads();
    if (t < MID_) hid[t] = fmaxf(pA[t] + pB[t] + ab1[t], 0.f);
    __syncthreads();
    if (t < 8) {
        float acc = ab2[t];
        const float* wv = aw2 + (size_t)t * MID_;
        for (int i = 0; i < MID_; ++i) acc = fmaf(hid[i], wv[i], acc);
        out[bb * 8 + t] = tanhf(acc);
    }
    if (bb == 0 && t >= 8 && t < 16) out[128 + (t - 8)] = expf(avar[t - 8]);
}

// ---------------------------------------------------------------------------
extern "C" void kernel_launch(void* const* d_in, const int* in_sizes, int n_in,
                              void* d_out, int out_size, void* d_ws, size_t ws_size,
                              hipStream_t stream) {
    const float* news = (const float*)d_in[0];
    const float* sf   = (const float*)d_in[1];
    const float* w3   = (const float*)d_in[2];  const float* b3 = (const float*)d_in[3];
    const float* w4   = (const float*)d_in[4];  const float* b4 = (const float*)d_in[5];
    const float* w5   = (const float*)d_in[6];  const float* b5 = (const float*)d_in[7];
    const float* w_ih = (const float*)d_in[8];  const float* w_hh = (const float*)d_in[9];
    const float* b_ih = (const float*)d_in[10]; const float* b_hh = (const float*)d_in[11];
    const float* lxw  = (const float*)d_in[12]; const float* lxb = (const float*)d_in[13];
    const float* lyw  = (const float*)d_in[14]; const float* lyb = (const float*)d_in[15];
    const float* w1   = (const float*)d_in[16]; const float* b1 = (const float*)d_in[17];
    const float* w2   = (const float*)d_in[18]; const float* b2 = (const float*)d_in[19];
    const float* aw1  = (const float*)d_in[20]; const float* ab1 = (const float*)d_in[21];
    const float* aw2  = (const float*)d_in[22]; const float* ab2 = (const float*)d_in[23];
    const float* avar = (const float*)d_in[24];

    char* ws = (char*)d_ws;
    u16*   wpack2  = (u16*)ws;                                  // 7,700,480 B
    u16*   wpre2   = (u16*)(ws + 7700480);                      // 2,621,440 B
    float* bcomb   = (float*)(ws + 10321920);                   // 10,240 B
    u16*   text_bf = (u16*)(ws + 10332160);                     // 819,200 B
    float* pre     = (float*)(ws + 11151360);                   // 2,621,440 B
    float* total   = (float*)(ws + 13772800);                   // 32,768 B
    float* lxwT    = (float*)(ws + 13805568);                   // 1,048,576 B
    float* lywT    = (float*)(ws + 14854144);                   // 262,144 B
    float* aw1T    = (float*)(ws + 15116288);                   // 540,672 B (end ~15.7 MB)

    prep<<<1024, 256, 0, stream>>>(w3, b3, w4, b4, w5, b5, w_ih, lxw, lyw, aw1,
                                   wpack2, wpre2, bcomb, lxwT, lywT, aw1T);
    conv_mfma<<<256, 512, 0, stream>>>(news, wpack2, bcomb, text_bf);
    lstm_pre_mfma<<<S_ * D_, 256, 0, stream>>>(text_bf, wpre2, b_ih, b_hh, pre);
    lstm_tail<<<S_ * B_, 512, 0, stream>>>(pre, w_hh, lxwT, lxb, lywT, lyb, total);
    head_feats<<<B_, 512, 0, stream>>>(total, sf, w1, b1, w2, b2, aw1T, ab1, aw2, ab2, avar, (float*)d_out);
}

// Round 10
// 132.992 us; speedup vs baseline: 1.0708x; 1.0708x over previous
//
#include <hip/hip_runtime.h>
#include <math.h>

// Problem dims
#define S_   8
#define B_   16
#define D_   10
#define N_   32
#define E_   300
#define H_   128
#define G4_  512
#define SDIM_ 96
#define MID_ 256
#define TOT_ 528

typedef unsigned short u16;
typedef unsigned int u32;
typedef __attribute__((ext_vector_type(8))) short short8;
typedef __attribute__((ext_vector_type(4))) short short4v;
typedef __attribute__((ext_vector_type(4))) float f32x4;

// round-to-nearest-even f32 -> bf16
static __device__ __forceinline__ u16 f2bf(float f) {
    unsigned u = __builtin_bit_cast(unsigned, f);
    return (u16)((u + 0x7FFFu + ((u >> 16) & 1u)) >> 16);
}

// ---------------------------------------------------------------------------
// prep (coalesced, block-range dispatch; 873 blocks x 256):
//  [0,160):   wpack2[s][ks][c][q][j] via per-(s,cgroup16) LDS transpose.
//             reads: each channel's contiguous f32 row; writes: 1KB chunks.
//  [160,416): wpre2[s][ks][g][q][j] likewise (kk identity, no transpose).
//  [416,672): lxwT 32x32 tile transposes.  [672,736): lywT.  [736,872): aw1T.
//  [872]:     bcomb.
// ---------------------------------------------------------------------------
__global__ __launch_bounds__(256) void prep(
        const float* __restrict__ w3, const float* __restrict__ b3,
        const float* __restrict__ w4, const float* __restrict__ b4,
        const float* __restrict__ w5, const float* __restrict__ b5,
        const float* __restrict__ w_ih,
        const float* __restrict__ lxw, const float* __restrict__ lyw,
        const float* __restrict__ aw1,
        u16* __restrict__ wpack2, u16* __restrict__ wpre2,
        float* __restrict__ bcomb,
        float* __restrict__ lxwT, float* __restrict__ lywT,
        float* __restrict__ aw1T) {
    const int blk = blockIdx.x, tid = threadIdx.x;

    if (blk < 160) {                     // ---- wpack2 ----
        __shared__ u16 tile[16][1504];
        const int s = blk / 20, cg = blk % 20;
        // zero tile
        for (int i = tid; i < 16 * 752; i += 256)
            reinterpret_cast<u32*>(&tile[0][0])[i] = 0u;
        __syncthreads();
        // fill: channel ch, 16 lanes each
        const int ch = tid >> 4, lane = tid & 15;
        const int c = cg * 16 + ch;
        const float* src = nullptr; int cnt = 0, ktap = 3;
        if (c < 100)      { src = w3 + (size_t)((s * 100 + c      ) * 300) * 3; cnt = 900;  ktap = 3; }
        else if (c < 200) { src = w4 + (size_t)((s * 100 + c - 100) * 300) * 4; cnt = 1200; ktap = 4; }
        else if (c < 300) { src = w5 + (size_t)((s * 100 + c - 200) * 300) * 5; cnt = 1500; ktap = 5; }
        for (int p = lane; p < cnt; p += 16) {
            int e = p / ktap, tap = p - e * ktap;
            tile[ch][tap * 300 + e] = f2bf(src[p]);
        }
        __syncthreads();
        // emit 47 chunks of 512 u16 (1KB contiguous), one u32 per thread
        u32* dst0 = reinterpret_cast<u32*>(wpack2 + (size_t)s * 481280 + cg * 512);
        const int mch = tid >> 4, rem = (tid * 2) & 31;
        for (int ks = 0; ks < 47; ++ks) {
            u32 v = (u32)tile[mch][ks * 32 + rem] | ((u32)tile[mch][ks * 32 + rem + 1] << 16);
            dst0[(size_t)ks * 5120 + tid] = v;
        }
    } else if (blk < 416) {              // ---- wpre2 ----
        __shared__ u16 tile2[16][320];
        const int u = blk - 160, s = u >> 5, gg = u & 31;
        const int ch = tid >> 4, lane = tid & 15;
        const int g = gg * 16 + ch;
        const float* src = w_ih + (size_t)(s * 512 + g) * 300;
        for (int p = lane; p < 320; p += 16)
            tile2[ch][p] = (p < 300) ? f2bf(src[p]) : (u16)0;
        __syncthreads();
        u32* dst0 = reinterpret_cast<u32*>(wpre2 + (size_t)s * 163840 + gg * 512);
        const int mch = tid >> 4, rem = (tid * 2) & 31;
        for (int ks = 0; ks < 10; ++ks) {
            u32 v = (u32)tile2[mch][ks * 32 + rem] | ((u32)tile2[mch][ks * 32 + rem + 1] << 16);
            dst0[(size_t)ks * 8192 + tid] = v;
        }
    } else if (blk < 872) {              // ---- 32x32 transposes ----
        __shared__ float ldsT[32][33];
        const float* inp; float* outp;
        int inRS, outRS, i0, t0, ivalid = 32;
        if (blk < 672) {                 // lxwT: out[s][256][128] = in[s][128][256]^T
            int u = blk - 416, s = u >> 5, t32 = u & 31;
            int it = t32 >> 2, tt = t32 & 3;
            inp = lxw + (size_t)s * 128 * 256; outp = lxwT + (size_t)s * 256 * 128;
            inRS = 256; outRS = 128; i0 = it * 32; t0 = tt * 32;
        } else if (blk < 736) {          // lywT: out[s][128][64] = in[s][64][128]^T
            int u = blk - 672, s = u >> 3, t32 = u & 7;
            int it = t32 >> 1, tt = t32 & 1;
            inp = lyw + (size_t)s * 64 * 128; outp = lywT + (size_t)s * 128 * 64;
            inRS = 128; outRS = 64; i0 = it * 32; t0 = tt * 32;
        } else {                         // aw1T: out[528][256] = in[256][528]^T
            int u = blk - 736;           // 136 blocks: 17 i-tiles x 8 j-tiles
            int it = u >> 3, jt = u & 7;
            inp = aw1; outp = aw1T;
            inRS = 528; outRS = 256; i0 = it * 32; t0 = jt * 32;
            ivalid = (i0 + 32 <= 528) ? 32 : (528 - i0);
        }
        const int row = tid >> 3, cf = tid & 7;
        float4 v = make_float4(0.f, 0.f, 0.f, 0.f);
        if (cf * 4 < ivalid)
            v = *reinterpret_cast<const float4*>(inp + (size_t)(t0 + row) * inRS + i0 + cf * 4);
        ldsT[cf * 4 + 0][row] = v.x; ldsT[cf * 4 + 1][row] = v.y;
        ldsT[cf * 4 + 2][row] = v.z; ldsT[cf * 4 + 3][row] = v.w;
        __syncthreads();
        if (row < ivalid) {
            float4 w;
            w.x = ldsT[row][cf * 4 + 0]; w.y = ldsT[row][cf * 4 + 1];
            w.z = ldsT[row][cf * 4 + 2]; w.w = ldsT[row][cf * 4 + 3];
            *reinterpret_cast<float4*>(outp + (size_t)(i0 + row) * outRS + t0 + cf * 4) = w;
        }
    } else {                             // ---- bcomb ----
        for (int i = tid; i < 2560; i += 256) {
            int c = i % 320, s = i / 320;
            float bv = 0.f;
            if (c < 100)      bv = b3[s*100 + c];
            else if (c < 200) bv = b4[s*100 + c - 100];
            else if (c < 300) bv = b5[s*100 + c - 200];
            bcomb[i] = bv;
        }
    }
}

// ---------------------------------------------------------------------------
// conv via MFMA (unchanged from R9): block per (s,b,half) = 5 days, 512 thr
// = 8 waves (2m x 4n), wave C[80][80] = 5x5 16x16 tiles. A from xs LDS
// (window trick). B direct global->VGPR coalesced with 2-deep reg prefetch.
// No K-loop barriers. x staging batched 8-deep.
// ---------------------------------------------------------------------------
__global__ __launch_bounds__(512, 1) void conv_mfma(const float* __restrict__ news,
                                                    const u16* __restrict__ wpack2,
                                                    const float* __restrict__ bcomb,
                                                    u16* __restrict__ text_bf) {
    __shared__ u16 xs[5 * 10816];
    __shared__ float part[10][320];
    const int tid = threadIdx.x, bid = blockIdx.x;
    const int s = bid & 7, rr_ = bid >> 3, b = rr_ >> 1, half = rr_ & 1;
    const int l = tid & 63, wvi = tid >> 6;
    const int wm = wvi >> 2, wn = wvi & 3;
    const int q = l >> 4, r16 = l & 15;

    const u16* gp[5];
#pragma unroll
    for (int nt = 0; nt < 5; ++nt) {
        int c = wn * 80 + nt * 16 + r16;
        gp[nt] = wpack2 + (size_t)s * 481280 + c * 32 + q * 8;
    }

    short8 bf0[5], bf1[5];
#pragma unroll
    for (int nt = 0; nt < 5; ++nt) bf0[nt] = *reinterpret_cast<const short8*>(gp[nt]);
#pragma unroll
    for (int nt = 0; nt < 5; ++nt) bf1[nt] = *reinterpret_cast<const short8*>(gp[nt] + 10240);

    {
        const float4* xg = reinterpret_cast<const float4*>(
            news + (size_t)((b * 8 + s) * 10 + half * 5) * 9600);
        for (int base = 0; base < 12000; base += 4096) {
            float4 v[8];
#pragma unroll
            for (int j = 0; j < 8; ++j) {
                int idx = base + j * 512 + tid;
                if (idx < 12000) v[j] = xg[idx];
            }
#pragma unroll
            for (int j = 0; j < 8; ++j) {
                int idx = base + j * 512 + tid;
                if (idx < 12000) {
                    int day = idx / 2400, rem = idx - day * 2400;
                    ushort4 o;
                    o.x = f2bf(v[j].x); o.y = f2bf(v[j].y);
                    o.z = f2bf(v[j].z); o.w = f2bf(v[j].w);
                    *reinterpret_cast<ushort4*>(&xs[day * 10816 + rem * 4]) = o;
                }
            }
        }
        for (int i = tid; i < 1520; i += 512) {
            int day = i / 304, p = i - day * 304;
            *reinterpret_cast<unsigned*>(&xs[day * 10816 + 9600 + p * 2]) = 0u;
        }
    }
    __syncthreads();

    f32x4 acc[5][5];
#pragma unroll
    for (int mt = 0; mt < 5; ++mt)
#pragma unroll
        for (int nt = 0; nt < 5; ++nt) acc[mt][nt] = (f32x4)(0.f);

#define LOADA(dst, ks) do {                                                       \
    _Pragma("unroll")                                                             \
    for (int mt_ = 0; mt_ < 5; ++mt_) {                                           \
        int di_ = wm * 5 + mt_;                                                   \
        int off_ = (di_ >> 1) * 10816 + (((di_ & 1) << 4) + r16) * 300            \
                   + (ks) * 32 + q * 8;                                           \
        short4v lo_ = *reinterpret_cast<const short4v*>(&xs[off_]);               \
        short4v hi_ = *reinterpret_cast<const short4v*>(&xs[off_ + 4]);           \
        dst[mt_] = __builtin_shufflevector(lo_, hi_, 0, 1, 2, 3, 4, 5, 6, 7);     \
    } } while (0)

#define MFMAS(bfv, av) do {                                                       \
    _Pragma("unroll")                                                             \
    for (int nt_ = 0; nt_ < 5; ++nt_)                                             \
        _Pragma("unroll")                                                         \
        for (int mt_ = 0; mt_ < 5; ++mt_)                                         \
            acc[mt_][nt_] = __builtin_amdgcn_mfma_f32_16x16x32_bf16(av[mt_], bfv[nt_], acc[mt_][nt_], 0, 0, 0); \
    } while (0)

    for (int ks = 0; ks < 46; ks += 2) {
        short8 a0[5], a1[5];
        LOADA(a0, ks);
        MFMAS(bf0, a0);
#pragma unroll
        for (int nt = 0; nt < 5; ++nt)
            bf0[nt] = *reinterpret_cast<const short8*>(gp[nt] + (ks + 2) * 10240);

        LOADA(a1, ks + 1);
        MFMAS(bf1, a1);
        if (ks + 3 < 47) {
#pragma unroll
            for (int nt = 0; nt < 5; ++nt)
                bf1[nt] = *reinterpret_cast<const short8*>(gp[nt] + (ks + 3) * 10240);
        }
    }
    {
        short8 a0[5];
        LOADA(a0, 46);
        MFMAS(bf0, a0);
    }
#undef LOADA
#undef MFMAS

#pragma unroll
    for (int mt = 0; mt < 5; ++mt) {
        const int di = wm * 5 + mt;
        const int nwb = (di & 1) << 4;
#pragma unroll
        for (int nt = 0; nt < 5; ++nt) {
            int oc = wn * 80 + nt * 16 + r16;
            int L = (oc < 100) ? 30 : (oc < 200) ? 29 : 28;
            float mx = -3e38f;
#pragma unroll
            for (int rr = 0; rr < 4; ++rr) {
                int nw = nwb + q * 4 + rr;
                if (nw < L) mx = fmaxf(mx, acc[mt][nt][rr]);
            }
            mx = fmaxf(mx, __shfl_xor(mx, 16));
            mx = fmaxf(mx, __shfl_xor(mx, 32));
            if (l < 16) part[di][wn * 80 + nt * 16 + l] = mx;
        }
    }
    __syncthreads();
    for (int i = tid; i < 1600; i += 512) {
        int day = i / 320, oc = i - day * 320;
        float mx = fmaxf(part[2 * day][oc], part[2 * day + 1][oc]);
        text_bf[((size_t)(s * 16 + b) * 10 + half * 5 + day) * 320 + oc] =
            f2bf(mx + bcomb[s * 320 + oc]);
    }
}

// ---------------------------------------------------------------------------
// lstm_pre via MFMA (unchanged)
// ---------------------------------------------------------------------------
__global__ __launch_bounds__(256) void lstm_pre_mfma(const u16* __restrict__ text_bf,
                                                     const u16* __restrict__ wpre2,
                                                     const float* __restrict__ b_ih,
                                                     const float* __restrict__ b_hh,
                                                     float* __restrict__ pre) {
    __shared__ u16 as16[16 * 320];
    const int sd = blockIdx.x, s = sd / 10, d = sd % 10;
    const int tid = threadIdx.x, l = tid & 63, w = tid >> 6, q = l >> 4, r16 = l & 15;

    for (int i = tid; i < 640; i += 256) {
        int r = i / 40, c = i % 40;
        *reinterpret_cast<float4*>(as16 + r * 320 + ((c ^ (r & 7)) << 3)) =
            *reinterpret_cast<const float4*>(text_bf + ((size_t)(s * 16 + r) * 10 + d) * 320 + c * 8);
    }
    __syncthreads();

    const u16* gpb[8];
#pragma unroll
    for (int nt = 0; nt < 8; ++nt) {
        int g = w * 128 + nt * 16 + r16;
        gpb[nt] = wpre2 + (size_t)s * 163840 + g * 32 + q * 8;
    }

    f32x4 acc[8];
#pragma unroll
    for (int nt = 0; nt < 8; ++nt) acc[nt] = (f32x4)(0.f);

    for (int ks = 0; ks < 10; ++ks) {
        short8 a = *reinterpret_cast<const short8*>(
            as16 + r16 * 320 + (((ks * 4 + q) ^ (r16 & 7)) << 3));
#pragma unroll
        for (int nt = 0; nt < 8; ++nt) {
            short8 bf = *reinterpret_cast<const short8*>(gpb[nt] + ks * 16384);
            acc[nt] = __builtin_amdgcn_mfma_f32_16x16x32_bf16(a, bf, acc[nt], 0, 0, 0);
        }
    }

#pragma unroll
    for (int nt = 0; nt < 8; ++nt) {
        int g = w * 128 + nt * 16 + r16;
        float bias = b_ih[s * 512 + g] + b_hh[s * 512 + g];
#pragma unroll
        for (int r = 0; r < 4; ++r) {
            int brow = q * 4 + r;
            pre[((size_t)sd * 16 + brow) * 512 + g] = acc[nt][r] + bias;
        }
    }
}

// ---------------------------------------------------------------------------
// lstm_tail (unchanged)
// ---------------------------------------------------------------------------
__global__ __launch_bounds__(512) void lstm_tail(const float* __restrict__ pre,
                                                 const float* __restrict__ w_hh,
                                                 const float* __restrict__ lxwT, const float* __restrict__ lxb,
                                                 const float* __restrict__ lywT, const float* __restrict__ lyb,
                                                 float* __restrict__ total) {
    __shared__ float wchunk[128][129];
    __shared__ float h_lds[H_];
    __shared__ float gates[G4_];
    __shared__ float comb_l[256];
    __shared__ __align__(16) float hx[H_];
    const int sb = blockIdx.x;
    const int s = sb / B_, b = sb % B_;
    const int t = threadIdx.x;

    float wrs[128];
    for (int c = 0; c < 4; ++c) {
        for (int i2 = t; i2 < 128 * 32; i2 += 512) {
            int row = i2 >> 5, fq = i2 & 31;
            float4 v = *reinterpret_cast<const float4*>(
                w_hh + ((size_t)(s * G4_ + c * 128 + row)) * H_ + fq * 4);
            wchunk[row][fq * 4 + 0] = v.x; wchunk[row][fq * 4 + 1] = v.y;
            wchunk[row][fq * 4 + 2] = v.z; wchunk[row][fq * 4 + 3] = v.w;
        }
        __syncthreads();
        if ((t >> 7) == c) {
            int r = t & 127;
#pragma unroll
            for (int i = 0; i < 128; ++i) wrs[i] = wchunk[r][i];
        }
        __syncthreads();
    }

    float cc = 0.f, hsum = 0.f, hval = 0.f;
    if (t < H_) h_lds[t] = 0.f;
    __syncthreads();

    for (int d = 0; d < D_; ++d) {
        float a0 = pre[(((size_t)(s * D_ + d) * B_ + b)) * G4_ + t];
        float a1 = 0.f, a2 = 0.f, a3 = 0.f;
#pragma unroll
        for (int i = 0; i < 128; i += 4) {
            float4 h4 = *reinterpret_cast<const float4*>(&h_lds[i]);
            a0 = fmaf(wrs[i + 0], h4.x, a0);
            a1 = fmaf(wrs[i + 1], h4.y, a1);
            a2 = fmaf(wrs[i + 2], h4.z, a2);
            a3 = fmaf(wrs[i + 3], h4.w, a3);
        }
        gates[t] = (a0 + a1) + (a2 + a3);
        __syncthreads();
        if (t < H_) {
            float ig = 1.f / (1.f + expf(-gates[t]));
            float fg = 1.f / (1.f + expf(-gates[H_ + t]));
            float gg = tanhf(gates[2 * H_ + t]);
            float og = 1.f / (1.f + expf(-gates[3 * H_ + t]));
            cc = fg * cc + ig * gg;
            hval = og * tanhf(cc);
            hsum += hval;
            h_lds[t] = hval;
        }
        __syncthreads();
    }
    if (t < H_) { comb_l[t] = hval; comb_l[H_ + t] = hsum; }
    __syncthreads();
    if (t < H_) {
        const float* wv = lxwT + (size_t)s * 256 * 128 + t;
        float a0 = lxb[s * H_ + t], a1 = 0.f;
        for (int i = 0; i < 256; i += 2) {
            a0 = fmaf(comb_l[i], wv[(size_t)i * 128], a0);
            a1 = fmaf(comb_l[i + 1], wv[(size_t)(i + 1) * 128], a1);
        }
        hx[t] = fmaxf(a0 + a1, 0.f);
    }
    __syncthreads();
    if (t < 64) {
        const float* wv = lywT + (size_t)s * 128 * 64 + t;
        float a0 = lyb[s * 64 + t], a1 = 0.f;
        for (int i = 0; i < 128; i += 2) {
            a0 = fmaf(hx[i], wv[(size_t)i * 64], a0);
            a1 = fmaf(hx[i + 1], wv[(size_t)(i + 1) * 64], a1);
        }
        total[(size_t)b * 512 + s * 64 + t] = fmaxf(a0 + a1, 0.f);
    }
}

// ---------------------------------------------------------------------------
// head_feats (unchanged)
// ---------------------------------------------------------------------------
__global__ __launch_bounds__(512) void head_feats(const float* __restrict__ total,
                                                  const float* __restrict__ sf,
                                                  const float* __restrict__ w1, const float* __restrict__ b1,
                                                  const float* __restrict__ w2, const float* __restrict__ b2,
                                                  const float* __restrict__ aw1T, const float* __restrict__ ab1,
                                                  const float* __restrict__ aw2, const float* __restrict__ ab2,
                                                  const float* __restrict__ avar,
                                                  float* __restrict__ out) {
    __shared__ __align__(16) float tr[TOT_];
    __shared__ float hid[MID_];
    __shared__ float h1f[24];
    __shared__ float pA[MID_], pB[MID_];
    const int bb = blockIdx.x, t = threadIdx.x;
    if (t < 128)
        reinterpret_cast<float4*>(tr)[t] = reinterpret_cast<const float4*>(total + (size_t)bb * 512)[t];
    if (t < 24) {
        float acc = b1[t];
        for (int i = 0; i < SDIM_; ++i) acc = fmaf(sf[bb * SDIM_ + i], w1[t * SDIM_ + i], acc);
        h1f[t] = fmaxf(acc, 0.f);
    }
    __syncthreads();
    if (t < 16) {
        float acc = b2[t];
        for (int i = 0; i < 24; ++i) acc = fmaf(h1f[i], w2[t * 24 + i], acc);
        tr[512 + t] = acc;
    }
    __syncthreads();
    {
        const int j = t & 255, hf = t >> 8;
        const int ilo = hf ? 264 : 0, ihi = hf ? 528 : 264;
        const float* wv = aw1T + j;
        float a0 = 0.f, a1 = 0.f, a2 = 0.f, a3 = 0.f;
        for (int i = ilo; i < ihi; i += 4) {
            a0 = fmaf(tr[i + 0], wv[(size_t)(i + 0) * 256], a0);
            a1 = fmaf(tr[i + 1], wv[(size_t)(i + 1) * 256], a1);
            a2 = fmaf(tr[i + 2], wv[(size_t)(i + 2) * 256], a2);
            a3 = fmaf(tr[i + 3], wv[(size_t)(i + 3) * 256], a3);
        }
        float p = (a0 + a1) + (a2 + a3);
        if (hf) pB[j] = p; else pA[j] = p;
    }
    __syncthreads();
    if (t < MID_) hid[t] = fmaxf(pA[t] + pB[t] + ab1[t], 0.f);
    __syncthreads();
    if (t < 8) {
        float acc = ab2[t];
        const float* wv = aw2 + (size_t)t * MID_;
        for (int i = 0; i < MID_; ++i) acc = fmaf(hid[i], wv[i], acc);
        out[bb * 8 + t] = tanhf(acc);
    }
    if (bb == 0 && t >= 8 && t < 16) out[128 + (t - 8)] = expf(avar[t - 8]);
}

// ---------------------------------------------------------------------------
extern "C" void kernel_launch(void* const* d_in, const int* in_sizes, int n_in,
                              void* d_out, int out_size, void* d_ws, size_t ws_size,
                              hipStream_t stream) {
    const float* news = (const float*)d_in[0];
    const float* sf   = (const float*)d_in[1];
    const float* w3   = (const float*)d_in[2];  const float* b3 = (const float*)d_in[3];
    const float* w4   = (const float*)d_in[4];  const float* b4 = (const float*)d_in[5];
    const float* w5   = (const float*)d_in[6];  const float* b5 = (const float*)d_in[7];
    const float* w_ih = (const float*)d_in[8];  const float* w_hh = (const float*)d_in[9];
    const float* b_ih = (const float*)d_in[10]; const float* b_hh = (const float*)d_in[11];
    const float* lxw  = (const float*)d_in[12]; const float* lxb = (const float*)d_in[13];
    const float* lyw  = (const float*)d_in[14]; const float* lyb = (const float*)d_in[15];
    const float* w1   = (const float*)d_in[16]; const float* b1 = (const float*)d_in[17];
    const float* w2   = (const float*)d_in[18]; const float* b2 = (const float*)d_in[19];
    const float* aw1  = (const float*)d_in[20]; const float* ab1 = (const float*)d_in[21];
    const float* aw2  = (const float*)d_in[22]; const float* ab2 = (const float*)d_in[23];
    const float* avar = (const float*)d_in[24];

    char* ws = (char*)d_ws;
    u16*   wpack2  = (u16*)ws;                                  // 7,700,480 B
    u16*   wpre2   = (u16*)(ws + 7700480);                      // 2,621,440 B
    float* bcomb   = (float*)(ws + 10321920);                   // 10,240 B
    u16*   text_bf = (u16*)(ws + 10332160);                     // 819,200 B
    float* pre     = (float*)(ws + 11151360);                   // 2,621,440 B
    float* total   = (float*)(ws + 13772800);                   // 32,768 B
    float* lxwT    = (float*)(ws + 13805568);                   // 1,048,576 B
    float* lywT    = (float*)(ws + 14854144);                   // 262,144 B
    float* aw1T    = (float*)(ws + 15116288);                   // 540,672 B (end ~15.7 MB)

    prep<<<873, 256, 0, stream>>>(w3, b3, w4, b4, w5, b5, w_ih, lxw, lyw, aw1,
                                  wpack2, wpre2, bcomb, lxwT, lywT, aw1T);
    conv_mfma<<<256, 512, 0, stream>>>(news, wpack2, bcomb, text_bf);
    lstm_pre_mfma<<<S_ * D_, 256, 0, stream>>>(text_bf, wpre2, b_ih, b_hh, pre);
    lstm_tail<<<S_ * B_, 512, 0, stream>>>(pre, w_hh, lxwT, lxb, lywT, lyb, total);
    head_feats<<<B_, 512, 0, stream>>>(total, sf, w1, b1, w2, b2, aw1T, ab1, aw2, ab2, avar, (float*)d_out);
}

// Round 11
// 122.338 us; speedup vs baseline: 1.1640x; 1.0871x over previous
//
#include <hip/hip_runtime.h>
#include <math.h>

// Problem dims
#define S_   8
#define B_   16
#define D_   10
#define N_   32
#define E_   300
#define H_   128
#define G4_  512
#define SDIM_ 96
#define MID_ 256
#define TOT_ 528

typedef unsigned short u16;
typedef unsigned int u32;
typedef __attribute__((ext_vector_type(8))) short short8;
typedef __attribute__((ext_vector_type(4))) short short4v;
typedef __attribute__((ext_vector_type(4))) float f32x4;

// round-to-nearest-even f32 -> bf16
static __device__ __forceinline__ u16 f2bf(float f) {
    unsigned u = __builtin_bit_cast(unsigned, f);
    return (u16)((u + 0x7FFFu + ((u >> 16) & 1u)) >> 16);
}

// ---------------------------------------------------------------------------
// prep (unchanged from R10): coalesced block-range dispatch, 873 blocks x 256.
// ---------------------------------------------------------------------------
__global__ __launch_bounds__(256) void prep(
        const float* __restrict__ w3, const float* __restrict__ b3,
        const float* __restrict__ w4, const float* __restrict__ b4,
        const float* __restrict__ w5, const float* __restrict__ b5,
        const float* __restrict__ w_ih,
        const float* __restrict__ lxw, const float* __restrict__ lyw,
        const float* __restrict__ aw1,
        u16* __restrict__ wpack2, u16* __restrict__ wpre2,
        float* __restrict__ bcomb,
        float* __restrict__ lxwT, float* __restrict__ lywT,
        float* __restrict__ aw1T) {
    const int blk = blockIdx.x, tid = threadIdx.x;

    if (blk < 160) {                     // ---- wpack2 ----
        __shared__ u16 tile[16][1504];
        const int s = blk / 20, cg = blk % 20;
        for (int i = tid; i < 16 * 752; i += 256)
            reinterpret_cast<u32*>(&tile[0][0])[i] = 0u;
        __syncthreads();
        const int ch = tid >> 4, lane = tid & 15;
        const int c = cg * 16 + ch;
        const float* src = nullptr; int cnt = 0, ktap = 3;
        if (c < 100)      { src = w3 + (size_t)((s * 100 + c      ) * 300) * 3; cnt = 900;  ktap = 3; }
        else if (c < 200) { src = w4 + (size_t)((s * 100 + c - 100) * 300) * 4; cnt = 1200; ktap = 4; }
        else if (c < 300) { src = w5 + (size_t)((s * 100 + c - 200) * 300) * 5; cnt = 1500; ktap = 5; }
        for (int p = lane; p < cnt; p += 16) {
            int e = p / ktap, tap = p - e * ktap;
            tile[ch][tap * 300 + e] = f2bf(src[p]);
        }
        __syncthreads();
        u32* dst0 = reinterpret_cast<u32*>(wpack2 + (size_t)s * 481280 + cg * 512);
        const int mch = tid >> 4, rem = (tid * 2) & 31;
        for (int ks = 0; ks < 47; ++ks) {
            u32 v = (u32)tile[mch][ks * 32 + rem] | ((u32)tile[mch][ks * 32 + rem + 1] << 16);
            dst0[(size_t)ks * 5120 + tid] = v;
        }
    } else if (blk < 416) {              // ---- wpre2 ----
        __shared__ u16 tile2[16][320];
        const int u = blk - 160, s = u >> 5, gg = u & 31;
        const int ch = tid >> 4, lane = tid & 15;
        const int g = gg * 16 + ch;
        const float* src = w_ih + (size_t)(s * 512 + g) * 300;
        for (int p = lane; p < 320; p += 16)
            tile2[ch][p] = (p < 300) ? f2bf(src[p]) : (u16)0;
        __syncthreads();
        u32* dst0 = reinterpret_cast<u32*>(wpre2 + (size_t)s * 163840 + gg * 512);
        const int mch = tid >> 4, rem = (tid * 2) & 31;
        for (int ks = 0; ks < 10; ++ks) {
            u32 v = (u32)tile2[mch][ks * 32 + rem] | ((u32)tile2[mch][ks * 32 + rem + 1] << 16);
            dst0[(size_t)ks * 8192 + tid] = v;
        }
    } else if (blk < 872) {              // ---- 32x32 transposes ----
        __shared__ float ldsT[32][33];
        const float* inp; float* outp;
        int inRS, outRS, i0, t0, ivalid = 32;
        if (blk < 672) {
            int u = blk - 416, s = u >> 5, t32 = u & 31;
            int it = t32 >> 2, tt = t32 & 3;
            inp = lxw + (size_t)s * 128 * 256; outp = lxwT + (size_t)s * 256 * 128;
            inRS = 256; outRS = 128; i0 = it * 32; t0 = tt * 32;
        } else if (blk < 736) {
            int u = blk - 672, s = u >> 3, t32 = u & 7;
            int it = t32 >> 1, tt = t32 & 1;
            inp = lyw + (size_t)s * 64 * 128; outp = lywT + (size_t)s * 128 * 64;
            inRS = 128; outRS = 64; i0 = it * 32; t0 = tt * 32;
        } else {
            int u = blk - 736;
            int it = u >> 3, jt = u & 7;
            inp = aw1; outp = aw1T;
            inRS = 528; outRS = 256; i0 = it * 32; t0 = jt * 32;
            ivalid = (i0 + 32 <= 528) ? 32 : (528 - i0);
        }
        const int row = tid >> 3, cf = tid & 7;
        float4 v = make_float4(0.f, 0.f, 0.f, 0.f);
        if (cf * 4 < ivalid)
            v = *reinterpret_cast<const float4*>(inp + (size_t)(t0 + row) * inRS + i0 + cf * 4);
        ldsT[cf * 4 + 0][row] = v.x; ldsT[cf * 4 + 1][row] = v.y;
        ldsT[cf * 4 + 2][row] = v.z; ldsT[cf * 4 + 3][row] = v.w;
        __syncthreads();
        if (row < ivalid) {
            float4 w;
            w.x = ldsT[row][cf * 4 + 0]; w.y = ldsT[row][cf * 4 + 1];
            w.z = ldsT[row][cf * 4 + 2]; w.w = ldsT[row][cf * 4 + 3];
            *reinterpret_cast<float4*>(outp + (size_t)(i0 + row) * outRS + t0 + cf * 4) = w;
        }
    } else {                             // ---- bcomb ----
        for (int i = tid; i < 2560; i += 256) {
            int c = i % 320, s = i / 320;
            float bv = 0.f;
            if (c < 100)      bv = b3[s*100 + c];
            else if (c < 200) bv = b4[s*100 + c - 100];
            else if (c < 300) bv = b5[s*100 + c - 200];
            bcomb[i] = bv;
        }
    }
}

// ---------------------------------------------------------------------------
// conv via MFMA (unchanged from R10).
// ---------------------------------------------------------------------------
__global__ __launch_bounds__(512, 1) void conv_mfma(const float* __restrict__ news,
                                                    const u16* __restrict__ wpack2,
                                                    const float* __restrict__ bcomb,
                                                    u16* __restrict__ text_bf) {
    __shared__ u16 xs[5 * 10816];
    __shared__ float part[10][320];
    const int tid = threadIdx.x, bid = blockIdx.x;
    const int s = bid & 7, rr_ = bid >> 3, b = rr_ >> 1, half = rr_ & 1;
    const int l = tid & 63, wvi = tid >> 6;
    const int wm = wvi >> 2, wn = wvi & 3;
    const int q = l >> 4, r16 = l & 15;

    const u16* gp[5];
#pragma unroll
    for (int nt = 0; nt < 5; ++nt) {
        int c = wn * 80 + nt * 16 + r16;
        gp[nt] = wpack2 + (size_t)s * 481280 + c * 32 + q * 8;
    }

    short8 bf0[5], bf1[5];
#pragma unroll
    for (int nt = 0; nt < 5; ++nt) bf0[nt] = *reinterpret_cast<const short8*>(gp[nt]);
#pragma unroll
    for (int nt = 0; nt < 5; ++nt) bf1[nt] = *reinterpret_cast<const short8*>(gp[nt] + 10240);

    {
        const float4* xg = reinterpret_cast<const float4*>(
            news + (size_t)((b * 8 + s) * 10 + half * 5) * 9600);
        for (int base = 0; base < 12000; base += 4096) {
            float4 v[8];
#pragma unroll
            for (int j = 0; j < 8; ++j) {
                int idx = base + j * 512 + tid;
                if (idx < 12000) v[j] = xg[idx];
            }
#pragma unroll
            for (int j = 0; j < 8; ++j) {
                int idx = base + j * 512 + tid;
                if (idx < 12000) {
                    int day = idx / 2400, rem = idx - day * 2400;
                    ushort4 o;
                    o.x = f2bf(v[j].x); o.y = f2bf(v[j].y);
                    o.z = f2bf(v[j].z); o.w = f2bf(v[j].w);
                    *reinterpret_cast<ushort4*>(&xs[day * 10816 + rem * 4]) = o;
                }
            }
        }
        for (int i = tid; i < 1520; i += 512) {
            int day = i / 304, p = i - day * 304;
            *reinterpret_cast<unsigned*>(&xs[day * 10816 + 9600 + p * 2]) = 0u;
        }
    }
    __syncthreads();

    f32x4 acc[5][5];
#pragma unroll
    for (int mt = 0; mt < 5; ++mt)
#pragma unroll
        for (int nt = 0; nt < 5; ++nt) acc[mt][nt] = (f32x4)(0.f);

#define LOADA(dst, ks) do {                                                       \
    _Pragma("unroll")                                                             \
    for (int mt_ = 0; mt_ < 5; ++mt_) {                                           \
        int di_ = wm * 5 + mt_;                                                   \
        int off_ = (di_ >> 1) * 10816 + (((di_ & 1) << 4) + r16) * 300            \
                   + (ks) * 32 + q * 8;                                           \
        short4v lo_ = *reinterpret_cast<const short4v*>(&xs[off_]);               \
        short4v hi_ = *reinterpret_cast<const short4v*>(&xs[off_ + 4]);           \
        dst[mt_] = __builtin_shufflevector(lo_, hi_, 0, 1, 2, 3, 4, 5, 6, 7);     \
    } } while (0)

#define MFMAS(bfv, av) do {                                                       \
    _Pragma("unroll")                                                             \
    for (int nt_ = 0; nt_ < 5; ++nt_)                                             \
        _Pragma("unroll")                                                         \
        for (int mt_ = 0; mt_ < 5; ++mt_)                                         \
            acc[mt_][nt_] = __builtin_amdgcn_mfma_f32_16x16x32_bf16(av[mt_], bfv[nt_], acc[mt_][nt_], 0, 0, 0); \
    } while (0)

    for (int ks = 0; ks < 46; ks += 2) {
        short8 a0[5], a1[5];
        LOADA(a0, ks);
        MFMAS(bf0, a0);
#pragma unroll
        for (int nt = 0; nt < 5; ++nt)
            bf0[nt] = *reinterpret_cast<const short8*>(gp[nt] + (ks + 2) * 10240);

        LOADA(a1, ks + 1);
        MFMAS(bf1, a1);
        if (ks + 3 < 47) {
#pragma unroll
            for (int nt = 0; nt < 5; ++nt)
                bf1[nt] = *reinterpret_cast<const short8*>(gp[nt] + (ks + 3) * 10240);
        }
    }
    {
        short8 a0[5];
        LOADA(a0, 46);
        MFMAS(bf0, a0);
    }
#undef LOADA
#undef MFMAS

#pragma unroll
    for (int mt = 0; mt < 5; ++mt) {
        const int di = wm * 5 + mt;
        const int nwb = (di & 1) << 4;
#pragma unroll
        for (int nt = 0; nt < 5; ++nt) {
            int oc = wn * 80 + nt * 16 + r16;
            int L = (oc < 100) ? 30 : (oc < 200) ? 29 : 28;
            float mx = -3e38f;
#pragma unroll
            for (int rr = 0; rr < 4; ++rr) {
                int nw = nwb + q * 4 + rr;
                if (nw < L) mx = fmaxf(mx, acc[mt][nt][rr]);
            }
            mx = fmaxf(mx, __shfl_xor(mx, 16));
            mx = fmaxf(mx, __shfl_xor(mx, 32));
            if (l < 16) part[di][wn * 80 + nt * 16 + l] = mx;
        }
    }
    __syncthreads();
    for (int i = tid; i < 1600; i += 512) {
        int day = i / 320, oc = i - day * 320;
        float mx = fmaxf(part[2 * day][oc], part[2 * day + 1][oc]);
        text_bf[((size_t)(s * 16 + b) * 10 + half * 5 + day) * 320 + oc] =
            f2bf(mx + bcomb[s * 320 + oc]);
    }
}

// ---------------------------------------------------------------------------
// stock_tail: per (s,b) block (128 x 512 thr). Computes its own LSTM
// pre-activations via MFMA (A = 10x320 text rows padded to 16, B = wpre2
// coalesced), then sequential LSTM + degenerate attention + linX + linY.
// pre lives in LDS -- no global round-trip, no separate kernel.
// ---------------------------------------------------------------------------
__global__ __launch_bounds__(512) void stock_tail(const u16* __restrict__ text_bf,
                                                  const u16* __restrict__ wpre2,
                                                  const float* __restrict__ b_ih,
                                                  const float* __restrict__ b_hh,
                                                  const float* __restrict__ w_hh,
                                                  const float* __restrict__ lxwT, const float* __restrict__ lxb,
                                                  const float* __restrict__ lywT, const float* __restrict__ lyb,
                                                  float* __restrict__ total) {
    __shared__ u16 as16[16 * 320];
    __shared__ float pre_lds[D_][G4_];
    __shared__ float wchunk[128][129];
    __shared__ float h_lds[H_];
    __shared__ float gates[G4_];
    __shared__ float comb_l[256];
    __shared__ __align__(16) float hx[H_];
    const int sb = blockIdx.x;
    const int s = sb >> 4, b = sb & 15;
    const int t = threadIdx.x, l = t & 63, wv = t >> 6, q = l >> 4, r16 = l & 15;

    // stage A: rows r=0..9 = text_bf[s][b][r][:], rows 10..15 zero; XOR-swizzled
    for (int i = t; i < 640; i += 512) {
        int r = i / 40, c = i % 40;
        float4 v = make_float4(0.f, 0.f, 0.f, 0.f);
        if (r < D_)
            v = *reinterpret_cast<const float4*>(
                text_bf + ((size_t)((s * 16 + b) * D_ + r)) * 320 + c * 8);
        *reinterpret_cast<float4*>(as16 + r * 320 + ((c ^ (r & 7)) << 3)) = v;
    }
    __syncthreads();

    // MFMA: pre[16 rows][512 g]; wave wv owns g in [wv*64, wv*64+64)
    {
        const u16* gpb[4];
#pragma unroll
        for (int nt = 0; nt < 4; ++nt) {
            int g = wv * 64 + nt * 16 + r16;
            gpb[nt] = wpre2 + (size_t)s * 163840 + g * 32 + q * 8;
        }
        f32x4 acc[4];
#pragma unroll
        for (int nt = 0; nt < 4; ++nt) acc[nt] = (f32x4)(0.f);
        for (int ks = 0; ks < 10; ++ks) {
            short8 a = *reinterpret_cast<const short8*>(
                as16 + r16 * 320 + (((ks * 4 + q) ^ (r16 & 7)) << 3));
#pragma unroll
            for (int nt = 0; nt < 4; ++nt) {
                short8 bf = *reinterpret_cast<const short8*>(gpb[nt] + ks * 16384);
                acc[nt] = __builtin_amdgcn_mfma_f32_16x16x32_bf16(a, bf, acc[nt], 0, 0, 0);
            }
        }
#pragma unroll
        for (int nt = 0; nt < 4; ++nt) {
            int g = wv * 64 + nt * 16 + r16;
            float bias = b_ih[s * G4_ + g] + b_hh[s * G4_ + g];
#pragma unroll
            for (int rr = 0; rr < 4; ++rr) {
                int row = q * 4 + rr;
                if (row < D_) pre_lds[row][g] = acc[nt][rr] + bias;
            }
        }
    }

    // stage w_hh[s] rows into per-thread regs, coalesced via LDS
    float wrs[128];
    for (int c = 0; c < 4; ++c) {
        __syncthreads();
        for (int i2 = t; i2 < 128 * 32; i2 += 512) {
            int row = i2 >> 5, fq = i2 & 31;
            float4 v = *reinterpret_cast<const float4*>(
                w_hh + ((size_t)(s * G4_ + c * 128 + row)) * H_ + fq * 4);
            wchunk[row][fq * 4 + 0] = v.x; wchunk[row][fq * 4 + 1] = v.y;
            wchunk[row][fq * 4 + 2] = v.z; wchunk[row][fq * 4 + 3] = v.w;
        }
        __syncthreads();
        if ((t >> 7) == c) {
            int r = t & 127;
#pragma unroll
            for (int i = 0; i < 128; ++i) wrs[i] = wchunk[r][i];
        }
    }
    __syncthreads();

    float cc = 0.f, hsum = 0.f, hval = 0.f;
    if (t < H_) h_lds[t] = 0.f;
    __syncthreads();

    for (int d = 0; d < D_; ++d) {
        float a0 = pre_lds[d][t];
        float a1 = 0.f, a2 = 0.f, a3 = 0.f;
#pragma unroll
        for (int i = 0; i < 128; i += 4) {
            float4 h4 = *reinterpret_cast<const float4*>(&h_lds[i]);
            a0 = fmaf(wrs[i + 0], h4.x, a0);
            a1 = fmaf(wrs[i + 1], h4.y, a1);
            a2 = fmaf(wrs[i + 2], h4.z, a2);
            a3 = fmaf(wrs[i + 3], h4.w, a3);
        }
        gates[t] = (a0 + a1) + (a2 + a3);
        __syncthreads();
        if (t < H_) {
            float ig = 1.f / (1.f + expf(-gates[t]));
            float fg = 1.f / (1.f + expf(-gates[H_ + t]));
            float gg = tanhf(gates[2 * H_ + t]);
            float og = 1.f / (1.f + expf(-gates[3 * H_ + t]));
            cc = fg * cc + ig * gg;
            hval = og * tanhf(cc);
            hsum += hval;
            h_lds[t] = hval;
        }
        __syncthreads();
    }
    if (t < H_) { comb_l[t] = hval; comb_l[H_ + t] = hsum; }
    __syncthreads();
    if (t < H_) {                       // linX: coalesced lxwT[s][i][t]
        const float* wvp = lxwT + (size_t)s * 256 * 128 + t;
        float a0 = lxb[s * H_ + t], a1 = 0.f;
        for (int i = 0; i < 256; i += 2) {
            a0 = fmaf(comb_l[i], wvp[(size_t)i * 128], a0);
            a1 = fmaf(comb_l[i + 1], wvp[(size_t)(i + 1) * 128], a1);
        }
        hx[t] = fmaxf(a0 + a1, 0.f);
    }
    __syncthreads();
    if (t < 64) {                       // linY: coalesced lywT[s][i][t]
        const float* wvp = lywT + (size_t)s * 128 * 64 + t;
        float a0 = lyb[s * 64 + t], a1 = 0.f;
        for (int i = 0; i < 128; i += 2) {
            a0 = fmaf(hx[i], wvp[(size_t)i * 64], a0);
            a1 = fmaf(hx[i + 1], wvp[(size_t)(i + 1) * 64], a1);
        }
        total[(size_t)b * 512 + s * 64 + t] = fmaxf(a0 + a1, 0.f);
    }
}

// ---------------------------------------------------------------------------
// head_feats (unchanged)
// ---------------------------------------------------------------------------
__global__ __launch_bounds__(512) void head_feats(const float* __restrict__ total,
                                                  const float* __restrict__ sf,
                                                  const float* __restrict__ w1, const float* __restrict__ b1,
                                                  const float* __restrict__ w2, const float* __restrict__ b2,
                                                  const float* __restrict__ aw1T, const float* __restrict__ ab1,
                                                  const float* __restrict__ aw2, const float* __restrict__ ab2,
                                                  const float* __restrict__ avar,
                                                  float* __restrict__ out) {
    __shared__ __align__(16) float tr[TOT_];
    __shared__ float hid[MID_];
    __shared__ float h1f[24];
    __shared__ float pA[MID_], pB[MID_];
    const int bb = blockIdx.x, t = threadIdx.x;
    if (t < 128)
        reinterpret_cast<float4*>(tr)[t] = reinterpret_cast<const float4*>(total + (size_t)bb * 512)[t];
    if (t < 24) {
        float acc = b1[t];
        for (int i = 0; i < SDIM_; ++i) acc = fmaf(sf[bb * SDIM_ + i], w1[t * SDIM_ + i], acc);
        h1f[t] = fmaxf(acc, 0.f);
    }
    __syncthreads();
    if (t < 16) {
        float acc = b2[t];
        for (int i = 0; i < 24; ++i) acc = fmaf(h1f[i], w2[t * 24 + i], acc);
        tr[512 + t] = acc;
    }
    __syncthreads();
    {
        const int j = t & 255, hf = t >> 8;
        const int ilo = hf ? 264 : 0, ihi = hf ? 528 : 264;
        const float* wv = aw1T + j;
        float a0 = 0.f, a1 = 0.f, a2 = 0.f, a3 = 0.f;
        for (int i = ilo; i < ihi; i += 4) {
            a0 = fmaf(tr[i + 0], wv[(size_t)(i + 0) * 256], a0);
            a1 = fmaf(tr[i + 1], wv[(size_t)(i + 1) * 256], a1);
            a2 = fmaf(tr[i + 2], wv[(size_t)(i + 2) * 256], a2);
            a3 = fmaf(tr[i + 3], wv[(size_t)(i + 3) * 256], a3);
        }
        float p = (a0 + a1) + (a2 + a3);
        if (hf) pB[j] = p; else pA[j] = p;
    }
    __syncthreads();
    if (t < MID_) hid[t] = fmaxf(pA[t] + pB[t] + ab1[t], 0.f);
    __syncthreads();
    if (t < 8) {
        float acc = ab2[t];
        const float* wv = aw2 + (size_t)t * MID_;
        for (int i = 0; i < MID_; ++i) acc = fmaf(hid[i], wv[i], acc);
        out[bb * 8 + t] = tanhf(acc);
    }
    if (bb == 0 && t >= 8 && t < 16) out[128 + (t - 8)] = expf(avar[t - 8]);
}

// ---------------------------------------------------------------------------
extern "C" void kernel_launch(void* const* d_in, const int* in_sizes, int n_in,
                              void* d_out, int out_size, void* d_ws, size_t ws_size,
                              hipStream_t stream) {
    const float* news = (const float*)d_in[0];
    const float* sf   = (const float*)d_in[1];
    const float* w3   = (const float*)d_in[2];  const float* b3 = (const float*)d_in[3];
    const float* w4   = (const float*)d_in[4];  const float* b4 = (const float*)d_in[5];
    const float* w5   = (const float*)d_in[6];  const float* b5 = (const float*)d_in[7];
    const float* w_ih = (const float*)d_in[8];  const float* w_hh = (const float*)d_in[9];
    const float* b_ih = (const float*)d_in[10]; const float* b_hh = (const float*)d_in[11];
    const float* lxw  = (const float*)d_in[12]; const float* lxb = (const float*)d_in[13];
    const float* lyw  = (const float*)d_in[14]; const float* lyb = (const float*)d_in[15];
    const float* w1   = (const float*)d_in[16]; const float* b1 = (const float*)d_in[17];
    const float* w2   = (const float*)d_in[18]; const float* b2 = (const float*)d_in[19];
    const float* aw1  = (const float*)d_in[20]; const float* ab1 = (const float*)d_in[21];
    const float* aw2  = (const float*)d_in[22]; const float* ab2 = (const float*)d_in[23];
    const float* avar = (const float*)d_in[24];

    char* ws = (char*)d_ws;
    u16*   wpack2  = (u16*)ws;                                  // 7,700,480 B
    u16*   wpre2   = (u16*)(ws + 7700480);                      // 2,621,440 B
    float* bcomb   = (float*)(ws + 10321920);                   // 10,240 B
    u16*   text_bf = (u16*)(ws + 10332160);                     // 819,200 B
    float* total   = (float*)(ws + 11151360);                   // 32,768 B
    float* lxwT    = (float*)(ws + 11184128);                   // 1,048,576 B
    float* lywT    = (float*)(ws + 12232704);                   // 262,144 B
    float* aw1T    = (float*)(ws + 12494848);                   // 540,672 B (end ~13.0 MB)

    prep<<<873, 256, 0, stream>>>(w3, b3, w4, b4, w5, b5, w_ih, lxw, lyw, aw1,
                                  wpack2, wpre2, bcomb, lxwT, lywT, aw1T);
    conv_mfma<<<256, 512, 0, stream>>>(news, wpack2, bcomb, text_bf);
    stock_tail<<<S_ * B_, 512, 0, stream>>>(text_bf, wpre2, b_ih, b_hh, w_hh,
                                            lxwT, lxb, lywT, lyb, total);
    head_feats<<<B_, 512, 0, stream>>>(total, sf, w1, b1, w2, b2, aw1T, ab1, aw2, ab2, avar, (float*)d_out);
}